// Round 1
// baseline (618.112 us; speedup 1.0000x reference)
//
#include <hip/hip_runtime.h>

// Problem constants
#define B_ 32
#define C_ 64
#define O_ 64
#define H_ 128
#define W_ 128

// ---------------- ws layout (float offsets) ----------------
// S:      [B*C*9]        off 0       (18432)
// cond2:  [B*16]         off 18432   (512)
// dw:     [B*C*9]        off 18944   (18432)
// pw:     [B*O*C]        off 37376   (131072)
// dbias:  [B*O]          off 168448  (2048)
// psum:   [O][B*H]       off 170496  (262144)
// psq:    [O][B*H]       off 432640  (262144)
// scale:  [O]            off 694784  (64)
// shift:  [O]            off 694848  (64)
#define WS_S      0
#define WS_COND2  18432
#define WS_DW     18944
#define WS_PW     37376
#define WS_DBIAS  168448
#define WS_PSUM   170496
#define WS_PSQ    432640
#define WS_SCALE  694784
#define WS_SHIFT  694848

// K1: per-(b,c) strided sums S[b,c,kh,kw] = sum_{oh,ow<63} x[b,c,2oh+kh,2ow+kw]
__global__ void k_strided_sums(const float* __restrict__ x, float* __restrict__ Sout) {
    int t = threadIdx.x;
    int bc = blockIdx.x;                     // b*64 + c
    const float* xp = x + (size_t)bc * (H_ * W_);
    float a[9];
#pragma unroll
    for (int k = 0; k < 9; k++) a[k] = 0.f;
    for (int idx = t; idx < H_ * W_; idx += 256) {
        int h = idx >> 7, w = idx & 127;
        float v = xp[idx];
        bool h0 = ((h & 1) == 0) && (h <= 124);
        bool h1 = ((h & 1) == 1) && (h <= 125);
        bool h2 = ((h & 1) == 0) && (h >= 2);
        bool w0 = ((w & 1) == 0) && (w <= 124);
        bool w1 = ((w & 1) == 1) && (w <= 125);
        bool w2 = ((w & 1) == 0) && (w >= 2);
        if (h0) { if (w0) a[0] += v; if (w1) a[1] += v; if (w2) a[2] += v; }
        if (h1) { if (w0) a[3] += v; if (w1) a[4] += v; if (w2) a[5] += v; }
        if (h2) { if (w0) a[6] += v; if (w1) a[7] += v; if (w2) a[8] += v; }
    }
    __shared__ float red[4][9];
    int lane = t & 63, wv = t >> 6;
#pragma unroll
    for (int k = 0; k < 9; k++) {
        float v = a[k];
        for (int off = 32; off > 0; off >>= 1) v += __shfl_down(v, off);
        if (lane == 0) red[wv][k] = v;
    }
    __syncthreads();
    if (t < 9) Sout[(size_t)bc * 9 + t] = red[0][t] + red[1][t] + red[2][t] + red[3][t];
}

// K2: condition generator head (one block, 512 threads: t = b*16 + j)
__global__ void k_cond(const float* __restrict__ S, const float* __restrict__ w1,
                       const float* __restrict__ b1, const float* __restrict__ w2,
                       const float* __restrict__ b2, float* __restrict__ cond2) {
    int t = threadIdx.x;          // 0..511
    int b = t >> 4, j = t & 15;
    __shared__ float condp[512];
    const float* Sb = S + b * 576;
    const float* w1j = w1 + j * 576;
    float s = 0.f;
    for (int i = 0; i < 576; i++) s += Sb[i] * w1j[i];
    s = s * (1.f / 3969.f) + b1[j];
    condp[t] = fmaxf(s, 0.f);
    __syncthreads();
    float s2 = b2[j];
    for (int k = 0; k < 16; k++) s2 += condp[(b << 4) + k] * w2[j * 16 + k];
    cond2[t] = fmaxf(s2, 0.f);
}

// K3: dynamic weight generators (dw, pw, dbias)
__global__ void k_dyn(const float* __restrict__ cond2,
                      const float* __restrict__ wg_w, const float* __restrict__ wg_b,
                      const float* __restrict__ pg_w, const float* __restrict__ pg_b,
                      const float* __restrict__ bg_w, const float* __restrict__ bg_b,
                      float* __restrict__ dw, float* __restrict__ pw, float* __restrict__ dbias) {
    int idx = blockIdx.x * 256 + threadIdx.x;
    if (idx < 18432) {                       // dw: [B][576]
        int b = idx / 576, r = idx - b * 576;
        const float* cd = cond2 + b * 16;
        float s = wg_b[r];
#pragma unroll
        for (int j = 0; j < 16; j++) s += cd[j] * wg_w[r * 16 + j];
        dw[idx] = fmaxf(s, 0.f);
    } else if (idx < 18432 + 131072) {       // pw: [B][4096]
        int k = idx - 18432;
        int b = k >> 12, r = k & 4095;
        const float* cd = cond2 + b * 16;
        float s = pg_b[r];
#pragma unroll
        for (int j = 0; j < 16; j++) s += cd[j] * pg_w[r * 16 + j];
        pw[k] = fmaxf(s, 0.f);
    } else if (idx < 151552) {               // dbias: [B][64]
        int k = idx - 149504;
        int b = k >> 6, r = k & 63;
        const float* cd = cond2 + b * 16;
        float s = bg_b[r];
#pragma unroll
        for (int j = 0; j < 16; j++) s += cd[j] * bg_w[r * 16 + j];
        dbias[k] = s;
    }
}

// K4: fused per-sample depthwise(3x3,pad1) + pointwise(1x1) + dbias,
//     write pre-BN out, emit per-(o,block) partial sum/sumsq.
// Grid: 4096 blocks = (b,h). Block: 256 thr: o = t&63, pg = t>>6 (4 pixel groups of 32).
__global__ void __launch_bounds__(256) k_fused(
        const float* __restrict__ x, const float* __restrict__ dw,
        const float* __restrict__ pw, const float* __restrict__ dbias,
        float* __restrict__ out, float* __restrict__ psum, float* __restrict__ psq) {
    int t = threadIdx.x;
    int bx = blockIdx.x;
    int b = bx >> 7, h = bx & 127;
    int o = t & 63, pg = t >> 6;

    __shared__ float pwT[4096];     // [c][o]
    __shared__ float xr[3][128];
    __shared__ float yr[128];
    __shared__ float dwv[9];
    __shared__ float dbl[64];
    __shared__ float reds[256];
    __shared__ float redq[256];

    // stage pw (transposed) + dbias
    const float* pwb = pw + (size_t)b * 4096;
#pragma unroll
    for (int k = 0; k < 16; k++) {
        int idx = t + k * 256;
        int oo = idx >> 6, cc = idx & 63;
        pwT[cc * 64 + oo] = pwb[idx];
    }
    if (t < 64) dbl[t] = dbias[b * 64 + t];

    float acc[32];
#pragma unroll
    for (int i = 0; i < 32; i++) acc[i] = 0.f;

    const size_t xb = (size_t)b * C_ * H_ * W_;
    for (int c = 0; c < C_; c++) {
        // load 3 input rows (zero-padded vertically) for channel c
        const float* xc = x + xb + (size_t)c * (H_ * W_);
        for (int i = t; i < 384; i += 256) {
            int r = i >> 7, w = i & 127;
            int hh = h + r - 1;
            xr[r][w] = (hh >= 0 && hh < 128) ? xc[hh * 128 + w] : 0.f;
        }
        if (t < 9) dwv[t] = dw[(size_t)(b * 64 + c) * 9 + t];
        __syncthreads();
        // depthwise stencil: 128 threads compute one y row
        if (t < 128) {
            float a = 0.f;
#pragma unroll
            for (int kh = 0; kh < 3; kh++) {
                float l = (t >= 1) ? xr[kh][t - 1] : 0.f;
                float m = xr[kh][t];
                float r = (t <= 126) ? xr[kh][t + 1] : 0.f;
                a = fmaf(dwv[kh * 3 + 0], l, a);
                a = fmaf(dwv[kh * 3 + 1], m, a);
                a = fmaf(dwv[kh * 3 + 2], r, a);
            }
            yr[t] = a;
        }
        __syncthreads();
        // pointwise accumulate
        float pwv = pwT[(c << 6) + o];
        const float4* yb4 = (const float4*)(yr + (pg << 5));
#pragma unroll
        for (int i = 0; i < 8; i++) {
            float4 y4 = yb4[i];
            acc[4 * i + 0] = fmaf(pwv, y4.x, acc[4 * i + 0]);
            acc[4 * i + 1] = fmaf(pwv, y4.y, acc[4 * i + 1]);
            acc[4 * i + 2] = fmaf(pwv, y4.z, acc[4 * i + 2]);
            acc[4 * i + 3] = fmaf(pwv, y4.w, acc[4 * i + 3]);
        }
        __syncthreads();   // protect yr/xr before next iteration rewrites
    }

    // epilogue: add dbias, store pre-BN out, accumulate BN partials
    float dbv = dbl[o];
    float s = 0.f, q = 0.f;
    size_t obase = ((size_t)(b * 64 + o) * 128 + h) * 128 + (pg << 5);
    float4* op = (float4*)(out + obase);
#pragma unroll
    for (int i = 0; i < 8; i++) {
        float4 v;
        v.x = acc[4 * i + 0] + dbv;
        v.y = acc[4 * i + 1] + dbv;
        v.z = acc[4 * i + 2] + dbv;
        v.w = acc[4 * i + 3] + dbv;
        s += v.x + v.y + v.z + v.w;
        q += v.x * v.x + v.y * v.y + v.z * v.z + v.w * v.w;
        op[i] = v;
    }
    reds[t] = s;
    redq[t] = q;
    __syncthreads();
    if (t < 64) {
        float ts = reds[t] + reds[t + 64] + reds[t + 128] + reds[t + 192];
        float tq = redq[t] + redq[t + 64] + redq[t + 128] + redq[t + 192];
        psum[(size_t)t * 4096 + bx] = ts;
        psq[(size_t)t * 4096 + bx] = tq;
    }
}

// K5: reduce partials -> scale/shift per channel
__global__ void k_bnstats(const float* __restrict__ psum, const float* __restrict__ psq,
                          const float* __restrict__ gamma, const float* __restrict__ beta,
                          float* __restrict__ scale, float* __restrict__ shift) {
    int o = blockIdx.x, t = threadIdx.x;
    float s = 0.f, q = 0.f;
    for (int i = t; i < 4096; i += 256) {
        s += psum[(size_t)o * 4096 + i];
        q += psq[(size_t)o * 4096 + i];
    }
    int lane = t & 63, wv = t >> 6;
    for (int off = 32; off > 0; off >>= 1) { s += __shfl_down(s, off); q += __shfl_down(q, off); }
    __shared__ float rs[4], rq[4];
    if (lane == 0) { rs[wv] = s; rq[wv] = q; }
    __syncthreads();
    if (t == 0) {
        float S = rs[0] + rs[1] + rs[2] + rs[3];
        float Q = rq[0] + rq[1] + rq[2] + rq[3];
        const float invN = 1.f / (float)(B_ * H_ * W_);
        float mean = S * invN;
        float var = fmaxf(Q * invN - mean * mean, 0.f);
        float sc = gamma[o] * rsqrtf(var + 1e-5f);
        scale[o] = sc;
        shift[o] = beta[o] - mean * sc;
    }
}

// K6: in-place BN apply (float4 grid-stride)
__global__ void k_bnapply(float* __restrict__ out, const float* __restrict__ scale,
                          const float* __restrict__ shift) {
    const int total4 = B_ * O_ * H_ * W_ / 4;   // 8388608
    float4* o4 = (float4*)out;
    for (int i = blockIdx.x * 256 + threadIdx.x; i < total4; i += gridDim.x * 256) {
        int o = (i >> 12) & 63;                 // 4096 float4 per (b,o) plane
        float sc = scale[o], sh = shift[o];
        float4 v = o4[i];
        v.x = fmaf(v.x, sc, sh);
        v.y = fmaf(v.y, sc, sh);
        v.z = fmaf(v.z, sc, sh);
        v.w = fmaf(v.w, sc, sh);
        o4[i] = v;
    }
}

extern "C" void kernel_launch(void* const* d_in, const int* in_sizes, int n_in,
                              void* d_out, int out_size, void* d_ws, size_t ws_size,
                              hipStream_t stream) {
    const float* x     = (const float*)d_in[0];
    const float* cg_w1 = (const float*)d_in[1];
    const float* cg_b1 = (const float*)d_in[2];
    const float* cg_w2 = (const float*)d_in[3];
    const float* cg_b2 = (const float*)d_in[4];
    const float* wg_w  = (const float*)d_in[5];
    const float* wg_b  = (const float*)d_in[6];
    const float* pg_w  = (const float*)d_in[7];
    const float* pg_b  = (const float*)d_in[8];
    const float* bg_w  = (const float*)d_in[9];
    const float* bg_b  = (const float*)d_in[10];
    const float* bn_g  = (const float*)d_in[11];
    const float* bn_b  = (const float*)d_in[12];
    float* out = (float*)d_out;
    float* ws  = (float*)d_ws;

    float* S     = ws + WS_S;
    float* cond2 = ws + WS_COND2;
    float* dw    = ws + WS_DW;
    float* pw    = ws + WS_PW;
    float* dbias = ws + WS_DBIAS;
    float* psum  = ws + WS_PSUM;
    float* psq   = ws + WS_PSQ;
    float* scale = ws + WS_SCALE;
    float* shift = ws + WS_SHIFT;

    k_strided_sums<<<B_ * C_, 256, 0, stream>>>(x, S);
    k_cond<<<1, 512, 0, stream>>>(S, cg_w1, cg_b1, cg_w2, cg_b2, cond2);
    k_dyn<<<(151552 + 255) / 256, 256, 0, stream>>>(cond2, wg_w, wg_b, pg_w, pg_b,
                                                    bg_w, bg_b, dw, pw, dbias);
    k_fused<<<B_ * H_, 256, 0, stream>>>(x, dw, pw, dbias, out, psum, psq);
    k_bnstats<<<O_, 256, 0, stream>>>(psum, psq, bn_g, bn_b, scale, shift);
    k_bnapply<<<4096, 256, 0, stream>>>(out, scale, shift);
}

// Round 2
// 509.777 us; speedup vs baseline: 1.2125x; 1.2125x over previous
//
#include <hip/hip_runtime.h>

// Problem constants
#define B_ 32
#define C_ 64
#define O_ 64
#define H_ 128
#define W_ 128

// ---------------- ws layout (float offsets) ----------------
#define WS_S      0         // [B*C*9]
#define WS_COND2  18432     // [B*16]
#define WS_DW     18944     // [B*C*9]
#define WS_PW     37376     // [B*O*C]
#define WS_DBIAS  168448    // [B*O]
#define WS_PSUM   170496    // [B*H][O]
#define WS_PSQ    432640    // [B*H][O]
#define WS_SCALE  694784    // [O]
#define WS_SHIFT  694848    // [O]

// K1: per-(b,c) strided sums S[b,c,kh,kw] = sum_{oh,ow<63} x[b,c,2oh+kh,2ow+kw]
// float4 loads, branchless mask-FMA.
__global__ void __launch_bounds__(256) k_strided_sums(const float* __restrict__ x,
                                                      float* __restrict__ Sout) {
    int t = threadIdx.x;
    int bc = blockIdx.x;                      // b*64 + c
    const float4* xp = (const float4*)(x + (size_t)bc * (H_ * W_));
    float a[9];
#pragma unroll
    for (int k = 0; k < 9; k++) a[k] = 0.f;
#pragma unroll
    for (int k = 0; k < 16; k++) {
        int i4 = t + k * 256;                 // 4096 float4 per plane
        int h = i4 >> 5;
        int w0 = (i4 & 31) << 2;
        float4 v = xp[i4];
        // kw masks: kw0 = even w<=124, kw1 = odd w<=125, kw2 = even 2<=w<=126
        float mA = (w0 == 124) ? 0.f : 1.f;   // drops w=126 from kw0, w=127 from kw1
        float mB = (w0 == 0) ? 0.f : 1.f;     // drops w=0 from kw2
        float rs0 = v.x + mA * v.z;
        float rs1 = v.y + mA * v.w;
        float rs2 = mB * v.x + v.z;
        float e  = (h & 1) ? 0.f : 1.f;
        float od = 1.f - e;
        float hm0 = (h == 126) ? 0.f : e;     // kh0: even h<=124
        float hm2 = (h == 0)   ? 0.f : e;     // kh2: even h>=2
        float hm1 = (h == 127) ? 0.f : od;    // kh1: odd h<=125
        a[0] = fmaf(hm0, rs0, a[0]); a[1] = fmaf(hm0, rs1, a[1]); a[2] = fmaf(hm0, rs2, a[2]);
        a[3] = fmaf(hm1, rs0, a[3]); a[4] = fmaf(hm1, rs1, a[4]); a[5] = fmaf(hm1, rs2, a[5]);
        a[6] = fmaf(hm2, rs0, a[6]); a[7] = fmaf(hm2, rs1, a[7]); a[8] = fmaf(hm2, rs2, a[8]);
    }
    __shared__ float red[4][9];
    int lane = t & 63, wv = t >> 6;
#pragma unroll
    for (int k = 0; k < 9; k++) {
        float v = a[k];
        for (int off = 32; off > 0; off >>= 1) v += __shfl_down(v, off);
        if (lane == 0) red[wv][k] = v;
    }
    __syncthreads();
    if (t < 9) Sout[(size_t)bc * 9 + t] = red[0][t] + red[1][t] + red[2][t] + red[3][t];
}

// K2: condition generator, one block per sample b. 256 thr: j = t>>4, seg = t&15.
__global__ void __launch_bounds__(256) k_cond(const float* __restrict__ S,
                       const float* __restrict__ w1, const float* __restrict__ b1,
                       const float* __restrict__ w2, const float* __restrict__ b2,
                       float* __restrict__ cond2) {
    int b = blockIdx.x;
    int t = threadIdx.x;
    int j = t >> 4, seg = t & 15;
    const float* Sb = S + b * 576;
    const float* w1j = w1 + j * 576;
    int i0 = seg * 36;
    float s = 0.f;
#pragma unroll 4
    for (int i = 0; i < 36; i++) s = fmaf(Sb[i0 + i], w1j[i0 + i], s);
    __shared__ float red[16][16];
    __shared__ float condv[16];
    red[j][seg] = s;
    __syncthreads();
    if (t < 16) {
        float acc = 0.f;
#pragma unroll
        for (int k = 0; k < 16; k++) acc += red[t][k];
        acc = acc * (1.f / 3969.f) + b1[t];
        condv[t] = fmaxf(acc, 0.f);
    }
    __syncthreads();
    if (t < 16) {
        float s2 = b2[t];
#pragma unroll
        for (int k = 0; k < 16; k++) s2 = fmaf(condv[k], w2[t * 16 + k], s2);
        cond2[b * 16 + t] = fmaxf(s2, 0.f);
    }
}

// K3: dynamic weight generators (dw, pw, dbias)
__global__ void k_dyn(const float* __restrict__ cond2,
                      const float* __restrict__ wg_w, const float* __restrict__ wg_b,
                      const float* __restrict__ pg_w, const float* __restrict__ pg_b,
                      const float* __restrict__ bg_w, const float* __restrict__ bg_b,
                      float* __restrict__ dw, float* __restrict__ pw, float* __restrict__ dbias) {
    int idx = blockIdx.x * 256 + threadIdx.x;
    if (idx < 18432) {                       // dw: [B][576]
        int b = idx / 576, r = idx - b * 576;
        const float* cd = cond2 + b * 16;
        float s = wg_b[r];
#pragma unroll
        for (int j = 0; j < 16; j++) s += cd[j] * wg_w[r * 16 + j];
        dw[idx] = fmaxf(s, 0.f);
    } else if (idx < 18432 + 131072) {       // pw: [B][4096]
        int k = idx - 18432;
        int b = k >> 12, r = k & 4095;
        const float* cd = cond2 + b * 16;
        float s = pg_b[r];
#pragma unroll
        for (int j = 0; j < 16; j++) s += cd[j] * pg_w[r * 16 + j];
        pw[k] = fmaxf(s, 0.f);
    } else if (idx < 151552) {               // dbias: [B][64]
        int k = idx - 149504;
        int b = k >> 6, r = k & 63;
        const float* cd = cond2 + b * 16;
        float s = bg_b[r];
#pragma unroll
        for (int j = 0; j < 16; j++) s += cd[j] * bg_w[r * 16 + j];
        dbias[k] = s;
    }
}

// K4: fused depthwise(3x3,pad1) + pointwise + dbias, pre-BN out + BN partials.
// Grid 4096 = (b,h). Block 256: o = t&63, pg = t>>6. 4 channels per iteration.
__global__ void __launch_bounds__(256) k_fused(
        const float* __restrict__ x, const float* __restrict__ dw,
        const float* __restrict__ pw, const float* __restrict__ dbias,
        float* __restrict__ out, float* __restrict__ psum, float* __restrict__ psq) {
    int t = threadIdx.x;
    int bx = blockIdx.x;
    int b = bx >> 7, h = bx & 127;
    int o = t & 63, pg = t >> 6;

    __shared__ float pwT[64 * 65];   // [c][o], stride 65 (conflict-free both ways)
    __shared__ float xr[4 * 3 * 128];
    __shared__ float yr[4 * 128];
    __shared__ float dwl[36];
    __shared__ float dbl[64];
    __shared__ float reds[256];
    __shared__ float redq[256];

    const float* pwb = pw + (size_t)b * 4096;
#pragma unroll
    for (int k = 0; k < 16; k++) {
        int idx = t + k * 256;
        int oo = idx >> 6, cc = idx & 63;
        pwT[cc * 65 + oo] = pwb[idx];
    }
    if (t < 64) dbl[t] = dbias[b * 64 + t];

    float acc[32];
#pragma unroll
    for (int i = 0; i < 32; i++) acc[i] = 0.f;

    const float* xb = x + ((size_t)b << 20);
    const float* dwb = dw + (size_t)b * 576;

    for (int cb = 0; cb < 64; cb += 4) {
        const float* xcb = xb + ((size_t)cb << 14);
        // stage 4 channels x 3 rows (zero-padded vertically): 1536 floats
#pragma unroll
        for (int k = 0; k < 6; k++) {
            int i = t + k * 256;
            int ci = i / 384;
            int rem = i - ci * 384;
            int rr = rem >> 7;
            int w = rem & 127;
            int hh = h + rr - 1;
            float v = 0.f;
            if (hh >= 0 && hh < 128) v = xcb[((size_t)ci << 14) + (hh << 7) + w];
            xr[i] = v;
        }
        if (t < 36) dwl[t] = dwb[cb * 9 + t];
        __syncthreads();
        // stencil: 512 outputs, 2 per thread (all 256 threads active)
#pragma unroll
        for (int s = 0; s < 2; s++) {
            int ci = (t >> 7) + 2 * s;
            int w = t & 127;
            const float* xcr = xr + ci * 384;
            const float* dv = dwl + ci * 9;
            float a = 0.f;
#pragma unroll
            for (int kh = 0; kh < 3; kh++) {
                const float* row = xcr + kh * 128;
                float l = (w >= 1) ? row[w - 1] : 0.f;
                float m = row[w];
                float r = (w <= 126) ? row[w + 1] : 0.f;
                a = fmaf(dv[kh * 3 + 0], l, a);
                a = fmaf(dv[kh * 3 + 1], m, a);
                a = fmaf(dv[kh * 3 + 2], r, a);
            }
            yr[ci * 128 + w] = a;
        }
        __syncthreads();
        // pointwise accumulate: 4 channels
#pragma unroll
        for (int ci = 0; ci < 4; ci++) {
            float pwv = pwT[(cb + ci) * 65 + o];
            const float4* y4 = (const float4*)(yr + ci * 128 + (pg << 5));
#pragma unroll
            for (int i = 0; i < 8; i++) {
                float4 v = y4[i];
                acc[4 * i + 0] = fmaf(pwv, v.x, acc[4 * i + 0]);
                acc[4 * i + 1] = fmaf(pwv, v.y, acc[4 * i + 1]);
                acc[4 * i + 2] = fmaf(pwv, v.z, acc[4 * i + 2]);
                acc[4 * i + 3] = fmaf(pwv, v.w, acc[4 * i + 3]);
            }
        }
        __syncthreads();
    }

    // epilogue
    float dbv = dbl[o];
    float s = 0.f, q = 0.f;
    size_t obase = (((size_t)(b * 64 + o)) << 14) + ((size_t)h << 7) + (size_t)(pg << 5);
    float4* op = (float4*)(out + obase);
#pragma unroll
    for (int i = 0; i < 8; i++) {
        float4 v;
        v.x = acc[4 * i + 0] + dbv;
        v.y = acc[4 * i + 1] + dbv;
        v.z = acc[4 * i + 2] + dbv;
        v.w = acc[4 * i + 3] + dbv;
        s += v.x + v.y + v.z + v.w;
        q += v.x * v.x + v.y * v.y + v.z * v.z + v.w * v.w;
        op[i] = v;
    }
    reds[t] = s;
    redq[t] = q;
    __syncthreads();
    if (t < 64) {
        float ts = reds[t] + reds[t + 64] + reds[t + 128] + reds[t + 192];
        float tq = redq[t] + redq[t + 64] + redq[t + 128] + redq[t + 192];
        psum[(size_t)bx * 64 + t] = ts;    // coalesced [bx][o]
        psq[(size_t)bx * 64 + t] = tq;
    }
}

// K5: reduce partials -> scale/shift per channel (psum layout [bx][o])
__global__ void k_bnstats(const float* __restrict__ psum, const float* __restrict__ psq,
                          const float* __restrict__ gamma, const float* __restrict__ beta,
                          float* __restrict__ scale, float* __restrict__ shift) {
    int o = blockIdx.x, t = threadIdx.x;
    float s = 0.f, q = 0.f;
    for (int i = t; i < 4096; i += 256) {
        s += psum[(size_t)i * 64 + o];
        q += psq[(size_t)i * 64 + o];
    }
    int lane = t & 63, wv = t >> 6;
    for (int off = 32; off > 0; off >>= 1) { s += __shfl_down(s, off); q += __shfl_down(q, off); }
    __shared__ float rs[4], rq[4];
    if (lane == 0) { rs[wv] = s; rq[wv] = q; }
    __syncthreads();
    if (t == 0) {
        float S = rs[0] + rs[1] + rs[2] + rs[3];
        float Q = rq[0] + rq[1] + rq[2] + rq[3];
        const float invN = 1.f / (float)(B_ * H_ * W_);
        float mean = S * invN;
        float var = fmaxf(Q * invN - mean * mean, 0.f);
        float sc = gamma[o] * rsqrtf(var + 1e-5f);
        scale[o] = sc;
        shift[o] = beta[o] - mean * sc;
    }
}

// K6: in-place BN apply (float4 grid-stride, scale/shift in LDS)
__global__ void __launch_bounds__(256) k_bnapply(float* __restrict__ out,
                          const float* __restrict__ scale, const float* __restrict__ shift) {
    __shared__ float ss[64], sh[64];
    int t = threadIdx.x;
    if (t < 64) { ss[t] = scale[t]; sh[t] = shift[t]; }
    __syncthreads();
    const int total4 = B_ * O_ * H_ * W_ / 4;   // 8388608
    float4* o4 = (float4*)out;
    for (int i = blockIdx.x * 256 + t; i < total4; i += gridDim.x * 256) {
        int o = (i >> 12) & 63;                 // 4096 float4 per (b,o) plane
        float sc = ss[o], sf = sh[o];
        float4 v = o4[i];
        v.x = fmaf(v.x, sc, sf);
        v.y = fmaf(v.y, sc, sf);
        v.z = fmaf(v.z, sc, sf);
        v.w = fmaf(v.w, sc, sf);
        o4[i] = v;
    }
}

extern "C" void kernel_launch(void* const* d_in, const int* in_sizes, int n_in,
                              void* d_out, int out_size, void* d_ws, size_t ws_size,
                              hipStream_t stream) {
    const float* x     = (const float*)d_in[0];
    const float* cg_w1 = (const float*)d_in[1];
    const float* cg_b1 = (const float*)d_in[2];
    const float* cg_w2 = (const float*)d_in[3];
    const float* cg_b2 = (const float*)d_in[4];
    const float* wg_w  = (const float*)d_in[5];
    const float* wg_b  = (const float*)d_in[6];
    const float* pg_w  = (const float*)d_in[7];
    const float* pg_b  = (const float*)d_in[8];
    const float* bg_w  = (const float*)d_in[9];
    const float* bg_b  = (const float*)d_in[10];
    const float* bn_g  = (const float*)d_in[11];
    const float* bn_b  = (const float*)d_in[12];
    float* out = (float*)d_out;
    float* ws  = (float*)d_ws;

    float* S     = ws + WS_S;
    float* cond2 = ws + WS_COND2;
    float* dw    = ws + WS_DW;
    float* pw    = ws + WS_PW;
    float* dbias = ws + WS_DBIAS;
    float* psum  = ws + WS_PSUM;
    float* psq   = ws + WS_PSQ;
    float* scale = ws + WS_SCALE;
    float* shift = ws + WS_SHIFT;

    k_strided_sums<<<B_ * C_, 256, 0, stream>>>(x, S);
    k_cond<<<B_, 256, 0, stream>>>(S, cg_w1, cg_b1, cg_w2, cg_b2, cond2);
    k_dyn<<<(151552 + 255) / 256, 256, 0, stream>>>(cond2, wg_w, wg_b, pg_w, pg_b,
                                                    bg_w, bg_b, dw, pw, dbias);
    k_fused<<<B_ * H_, 256, 0, stream>>>(x, dw, pw, dbias, out, psum, psq);
    k_bnstats<<<O_, 256, 0, stream>>>(psum, psq, bn_g, bn_b, scale, shift);
    k_bnapply<<<4096, 256, 0, stream>>>(out, scale, shift);
}

// Round 3
// 392.638 us; speedup vs baseline: 1.5743x; 1.2983x over previous
//
#include <hip/hip_runtime.h>

// Problem constants
#define B_ 32
#define C_ 64
#define O_ 64
#define H_ 128
#define W_ 128

typedef __attribute__((ext_vector_type(8))) short short8;   // 8 x bf16 (4 VGPRs)
typedef __attribute__((ext_vector_type(4))) float f32x4;    // 4 x fp32 acc

static __device__ __forceinline__ unsigned short f2bf(float f) {
    unsigned u = __builtin_bit_cast(unsigned, f);
    unsigned r = (u + 0x7FFFu + ((u >> 16) & 1u)) >> 16;    // RNE
    return (unsigned short)r;
}

// ---------------- ws layout (float offsets) ----------------
#define WS_S      0         // [B*C*9]              18432
#define WS_COND2  18432     // [B*16]               512
#define WS_DW     18944     // [B*C*9]              18432
#define WS_DBIAS  37376     // [B*O]                2048
#define WS_PWBF   39424     // [B*O*C] bf16         65536 float slots
#define WS_PSUM   104960    // [2048][64]           131072
#define WS_PSQ    236032    // [2048][64]           131072
#define WS_SCALE  367104    // [O]
#define WS_SHIFT  367168    // [O]

// K1: per-(b,c) strided sums (unchanged)
__global__ void __launch_bounds__(256) k_strided_sums(const float* __restrict__ x,
                                                      float* __restrict__ Sout) {
    int t = threadIdx.x;
    int bc = blockIdx.x;
    const float4* xp = (const float4*)(x + (size_t)bc * (H_ * W_));
    float a[9];
#pragma unroll
    for (int k = 0; k < 9; k++) a[k] = 0.f;
#pragma unroll
    for (int k = 0; k < 16; k++) {
        int i4 = t + k * 256;
        int h = i4 >> 5;
        int w0 = (i4 & 31) << 2;
        float4 v = xp[i4];
        float mA = (w0 == 124) ? 0.f : 1.f;
        float mB = (w0 == 0) ? 0.f : 1.f;
        float rs0 = v.x + mA * v.z;
        float rs1 = v.y + mA * v.w;
        float rs2 = mB * v.x + v.z;
        float e  = (h & 1) ? 0.f : 1.f;
        float od = 1.f - e;
        float hm0 = (h == 126) ? 0.f : e;
        float hm2 = (h == 0)   ? 0.f : e;
        float hm1 = (h == 127) ? 0.f : od;
        a[0] = fmaf(hm0, rs0, a[0]); a[1] = fmaf(hm0, rs1, a[1]); a[2] = fmaf(hm0, rs2, a[2]);
        a[3] = fmaf(hm1, rs0, a[3]); a[4] = fmaf(hm1, rs1, a[4]); a[5] = fmaf(hm1, rs2, a[5]);
        a[6] = fmaf(hm2, rs0, a[6]); a[7] = fmaf(hm2, rs1, a[7]); a[8] = fmaf(hm2, rs2, a[8]);
    }
    __shared__ float red[4][9];
    int lane = t & 63, wv = t >> 6;
#pragma unroll
    for (int k = 0; k < 9; k++) {
        float v = a[k];
        for (int off = 32; off > 0; off >>= 1) v += __shfl_down(v, off);
        if (lane == 0) red[wv][k] = v;
    }
    __syncthreads();
    if (t < 9) Sout[(size_t)bc * 9 + t] = red[0][t] + red[1][t] + red[2][t] + red[3][t];
}

// K2: condition generator (unchanged)
__global__ void __launch_bounds__(256) k_cond(const float* __restrict__ S,
                       const float* __restrict__ w1, const float* __restrict__ b1,
                       const float* __restrict__ w2, const float* __restrict__ b2,
                       float* __restrict__ cond2) {
    int b = blockIdx.x;
    int t = threadIdx.x;
    int j = t >> 4, seg = t & 15;
    const float* Sb = S + b * 576;
    const float* w1j = w1 + j * 576;
    int i0 = seg * 36;
    float s = 0.f;
#pragma unroll 4
    for (int i = 0; i < 36; i++) s = fmaf(Sb[i0 + i], w1j[i0 + i], s);
    __shared__ float red[16][16];
    __shared__ float condv[16];
    red[j][seg] = s;
    __syncthreads();
    if (t < 16) {
        float acc = 0.f;
#pragma unroll
        for (int k = 0; k < 16; k++) acc += red[t][k];
        acc = acc * (1.f / 3969.f) + b1[t];
        condv[t] = fmaxf(acc, 0.f);
    }
    __syncthreads();
    if (t < 16) {
        float s2 = b2[t];
#pragma unroll
        for (int k = 0; k < 16; k++) s2 = fmaf(condv[k], w2[t * 16 + k], s2);
        cond2[b * 16 + t] = fmaxf(s2, 0.f);
    }
}

// K3: dynamic generators; pw now emitted as bf16 [b][o][c]
__global__ void k_dyn(const float* __restrict__ cond2,
                      const float* __restrict__ wg_w, const float* __restrict__ wg_b,
                      const float* __restrict__ pg_w, const float* __restrict__ pg_b,
                      const float* __restrict__ bg_w, const float* __restrict__ bg_b,
                      float* __restrict__ dw, unsigned short* __restrict__ pwbf,
                      float* __restrict__ dbias) {
    int idx = blockIdx.x * 256 + threadIdx.x;
    if (idx < 18432) {                       // dw: [B][576]
        int b = idx / 576, r = idx - b * 576;
        const float* cd = cond2 + b * 16;
        float s = wg_b[r];
#pragma unroll
        for (int j = 0; j < 16; j++) s += cd[j] * wg_w[r * 16 + j];
        dw[idx] = fmaxf(s, 0.f);
    } else if (idx < 18432 + 131072) {       // pw: [B][O*C] -> bf16
        int k = idx - 18432;
        int b = k >> 12, r = k & 4095;
        const float* cd = cond2 + b * 16;
        float s = pg_b[r];
#pragma unroll
        for (int j = 0; j < 16; j++) s += cd[j] * pg_w[r * 16 + j];
        pwbf[k] = f2bf(fmaxf(s, 0.f));
    } else if (idx < 151552) {               // dbias: [B][64]
        int k = idx - 149504;
        int b = k >> 6, r = k & 63;
        const float* cd = cond2 + b * 16;
        float s = bg_b[r];
#pragma unroll
        for (int j = 0; j < 16; j++) s += cd[j] * bg_w[r * 16 + j];
        dbias[k] = s;
    }
}

// K4: fused depthwise (fp32 stencil) + MFMA pointwise (bf16 in, fp32 acc).
// Grid 2048 = (b, 2-row tile). Block 256 = 4 waves.
// Per block: out tile [64 o][256 px], px = h_loc*128 + w.
struct SM4 {
    union {
        unsigned short y[256 * 72];   // [px][c] bf16, pad 8 -> 36864 B
        float epi[32 * 260];          // [o_loc][px] fp32, pad 4 -> 33280 B
    };
    float xr[4 * 4 * 128];            // 4 ch x 4 rows x 128
    float dwl[576];
    float sred[256];
    float qred[256];
    float dbl[64];
};

__global__ void __launch_bounds__(256) k_fused(
        const float* __restrict__ x, const float* __restrict__ dw,
        const unsigned short* __restrict__ pwbf, const float* __restrict__ dbias,
        float* __restrict__ out, float* __restrict__ psum, float* __restrict__ psq) {
    __shared__ SM4 sm;
    int t = threadIdx.x;
    int bx = blockIdx.x;
    int b = bx >> 6;
    int pt = bx & 63;
    int h0 = pt << 1;

    int l = t & 63, w_id = t >> 6;
    int quad = l >> 4, l15 = l & 15;

    // stage dw weights + dbias
    for (int i = t; i < 576; i += 256) sm.dwl[i] = dw[b * 576 + i];
    if (t < 64) sm.dbl[t] = dbias[b * 64 + t];

    // preload pw B-fragments from global: B[k=c][n=o], lane: n=l15, k=quad*8+j
    short8 bfr[4][2];
    const unsigned short* pwb = pwbf + (size_t)b * 4096;
#pragma unroll
    for (int nt = 0; nt < 4; nt++)
#pragma unroll
        for (int ck = 0; ck < 2; ck++) {
            int o = nt * 16 + l15;
            int c0 = ck * 32 + quad * 8;
            bfr[nt][ck] = *(const short8*)(pwb + o * 64 + c0);
        }

    f32x4 acc[4][4];
#pragma unroll
    for (int i = 0; i < 4; i++)
#pragma unroll
        for (int j = 0; j < 4; j++) acc[i][j] = (f32x4){0.f, 0.f, 0.f, 0.f};

    // stencil mapping: c_loc = t>>6, 4 px per thread
    int c_loc = t >> 6;
    int pxg = t & 63;
    int px0 = pxg << 2;
    int h_loc = px0 >> 7;
    int w0 = px0 & 127;

    const float* xb = x + ((size_t)b << 20);

    for (int r = 0; r < 16; r++) {
        int cb = r << 2;
        const float* xcb = xb + ((size_t)cb << 14);
        // stage 4 ch x 4 rows (h0-1..h0+2): 512 float4, 2 per thread
#pragma unroll
        for (int k = 0; k < 2; k++) {
            int f4 = t + k * 256;
            int cc = f4 >> 7, rem = f4 & 127;
            int rr = rem >> 5, w4 = rem & 31;
            int hh = h0 - 1 + rr;
            float4 v = make_float4(0.f, 0.f, 0.f, 0.f);
            if (hh >= 0 && hh < 128) v = *(const float4*)(xcb + cc * 16384 + hh * 128 + (w4 << 2));
            *(float4*)&sm.xr[cc * 512 + rr * 128 + (w4 << 2)] = v;
        }
        __syncthreads();

        int cg = cb + c_loc;
        const float* dv = sm.dwl + cg * 9;
        const float* xc = sm.xr + c_loc * 512;
        float y0 = 0.f, y1 = 0.f, y2 = 0.f, y3 = 0.f;
#pragma unroll
        for (int kh = 0; kh < 3; kh++) {
            const float* row = xc + (h_loc + kh) * 128;
            float4 fc = *(const float4*)(row + w0);
            float4 fm = *(const float4*)(row + (w0 ? w0 - 4 : 0));
            float4 fp = *(const float4*)(row + ((w0 < 124) ? w0 + 4 : 120));
            float lft = w0 ? fm.w : 0.f;
            float rgt = (w0 < 124) ? fp.x : 0.f;
            float dA = dv[kh * 3 + 0], dB = dv[kh * 3 + 1], dC = dv[kh * 3 + 2];
            y0 = fmaf(dA, lft, fmaf(dB, fc.x, fmaf(dC, fc.y, y0)));
            y1 = fmaf(dA, fc.x, fmaf(dB, fc.y, fmaf(dC, fc.z, y1)));
            y2 = fmaf(dA, fc.y, fmaf(dB, fc.z, fmaf(dC, fc.w, y2)));
            y3 = fmaf(dA, fc.z, fmaf(dB, fc.w, fmaf(dC, rgt, y3)));
        }
        sm.y[(px0 + 0) * 72 + cg] = f2bf(y0);
        sm.y[(px0 + 1) * 72 + cg] = f2bf(y1);
        sm.y[(px0 + 2) * 72 + cg] = f2bf(y2);
        sm.y[(px0 + 3) * 72 + cg] = f2bf(y3);
        __syncthreads();
    }

    // MFMA phase: per wave 64 px (4 m-tiles) x 64 o (4 n-tiles), K=64 (2 chunks)
    int pxbase = w_id << 6;
#pragma unroll
    for (int ck = 0; ck < 2; ck++) {
        short8 afr[4];
#pragma unroll
        for (int mt = 0; mt < 4; mt++) {
            int px = pxbase + mt * 16 + l15;
            afr[mt] = *(const short8*)&sm.y[px * 72 + ck * 32 + quad * 8];
        }
#pragma unroll
        for (int nt = 0; nt < 4; nt++)
#pragma unroll
            for (int mt = 0; mt < 4; mt++)
                acc[mt][nt] = __builtin_amdgcn_mfma_f32_16x16x32_bf16(
                    afr[mt], bfr[nt][ck], acc[mt][nt], 0, 0, 0);
    }
    __syncthreads();   // all y reads done before epi reuses the union

    // epilogue: 2 o-chunks of 32
    float* outb = out + ((size_t)b << 20);
#pragma unroll
    for (int oc = 0; oc < 2; oc++) {
        // scatter acc tiles into epi[o_loc][px]
#pragma unroll
        for (int ni = 0; ni < 2; ni++) {
            int nt = oc * 2 + ni;
            int o_loc = ni * 16 + l15;
#pragma unroll
            for (int mt = 0; mt < 4; mt++) {
                int pxw = pxbase + mt * 16 + quad * 4;
                *(f32x4*)&sm.epi[o_loc * 260 + pxw] = acc[mt][nt];
            }
        }
        __syncthreads();
        // coalesced read + dbias + stats + store
        int o_loc2 = t >> 3;
        int o = oc * 32 + o_loc2;
        int p0 = (t & 7) << 5;
        float dbv = sm.dbl[o];
        float s = 0.f, q = 0.f;
        float* og = outb + (size_t)o * 16384 + h0 * 128 + p0;
#pragma unroll
        for (int i = 0; i < 8; i++) {
            float4 v = *(float4*)&sm.epi[o_loc2 * 260 + p0 + i * 4];
            v.x += dbv; v.y += dbv; v.z += dbv; v.w += dbv;
            s += v.x + v.y + v.z + v.w;
            q += v.x * v.x + v.y * v.y + v.z * v.z + v.w * v.w;
            *(float4*)(og + i * 4) = v;
        }
        sm.sred[t] = s;
        sm.qred[t] = q;
        __syncthreads();
        if (t < 32) {
            float S = 0.f, Q = 0.f;
#pragma unroll
            for (int j2 = 0; j2 < 8; j2++) { S += sm.sred[t * 8 + j2]; Q += sm.qred[t * 8 + j2]; }
            psum[(size_t)bx * 64 + oc * 32 + t] = S;
            psq[(size_t)bx * 64 + oc * 32 + t] = Q;
        }
        __syncthreads();
    }
}

// K5: reduce partials -> scale/shift (2048 tiles now)
__global__ void k_bnstats(const float* __restrict__ psum, const float* __restrict__ psq,
                          const float* __restrict__ gamma, const float* __restrict__ beta,
                          float* __restrict__ scale, float* __restrict__ shift) {
    int o = blockIdx.x, t = threadIdx.x;
    float s = 0.f, q = 0.f;
    for (int i = t; i < 2048; i += 256) {
        s += psum[(size_t)i * 64 + o];
        q += psq[(size_t)i * 64 + o];
    }
    int lane = t & 63, wv = t >> 6;
    for (int off = 32; off > 0; off >>= 1) { s += __shfl_down(s, off); q += __shfl_down(q, off); }
    __shared__ float rs[4], rq[4];
    if (lane == 0) { rs[wv] = s; rq[wv] = q; }
    __syncthreads();
    if (t == 0) {
        float S = rs[0] + rs[1] + rs[2] + rs[3];
        float Q = rq[0] + rq[1] + rq[2] + rq[3];
        const float invN = 1.f / (float)(B_ * H_ * W_);
        float mean = S * invN;
        float var = fmaxf(Q * invN - mean * mean, 0.f);
        float sc = gamma[o] * rsqrtf(var + 1e-5f);
        scale[o] = sc;
        shift[o] = beta[o] - mean * sc;
    }
}

// K6: in-place BN apply
__global__ void __launch_bounds__(256) k_bnapply(float* __restrict__ out,
                          const float* __restrict__ scale, const float* __restrict__ shift) {
    __shared__ float ss[64], sh[64];
    int t = threadIdx.x;
    if (t < 64) { ss[t] = scale[t]; sh[t] = shift[t]; }
    __syncthreads();
    const int total4 = B_ * O_ * H_ * W_ / 4;
    float4* o4 = (float4*)out;
    for (int i = blockIdx.x * 256 + t; i < total4; i += gridDim.x * 256) {
        int o = (i >> 12) & 63;
        float sc = ss[o], sf = sh[o];
        float4 v = o4[i];
        v.x = fmaf(v.x, sc, sf);
        v.y = fmaf(v.y, sc, sf);
        v.z = fmaf(v.z, sc, sf);
        v.w = fmaf(v.w, sc, sf);
        o4[i] = v;
    }
}

extern "C" void kernel_launch(void* const* d_in, const int* in_sizes, int n_in,
                              void* d_out, int out_size, void* d_ws, size_t ws_size,
                              hipStream_t stream) {
    const float* x     = (const float*)d_in[0];
    const float* cg_w1 = (const float*)d_in[1];
    const float* cg_b1 = (const float*)d_in[2];
    const float* cg_w2 = (const float*)d_in[3];
    const float* cg_b2 = (const float*)d_in[4];
    const float* wg_w  = (const float*)d_in[5];
    const float* wg_b  = (const float*)d_in[6];
    const float* pg_w  = (const float*)d_in[7];
    const float* pg_b  = (const float*)d_in[8];
    const float* bg_w  = (const float*)d_in[9];
    const float* bg_b  = (const float*)d_in[10];
    const float* bn_g  = (const float*)d_in[11];
    const float* bn_b  = (const float*)d_in[12];
    float* out = (float*)d_out;
    float* ws  = (float*)d_ws;

    float* S     = ws + WS_S;
    float* cond2 = ws + WS_COND2;
    float* dw    = ws + WS_DW;
    float* dbias = ws + WS_DBIAS;
    unsigned short* pwbf = (unsigned short*)(ws + WS_PWBF);
    float* psum  = ws + WS_PSUM;
    float* psq   = ws + WS_PSQ;
    float* scale = ws + WS_SCALE;
    float* shift = ws + WS_SHIFT;

    k_strided_sums<<<B_ * C_, 256, 0, stream>>>(x, S);
    k_cond<<<B_, 256, 0, stream>>>(S, cg_w1, cg_b1, cg_w2, cg_b2, cond2);
    k_dyn<<<(151552 + 255) / 256, 256, 0, stream>>>(cond2, wg_w, wg_b, pg_w, pg_b,
                                                    bg_w, bg_b, dw, pwbf, dbias);
    k_fused<<<2048, 256, 0, stream>>>(x, dw, pwbf, dbias, out, psum, psq);
    k_bnstats<<<O_, 256, 0, stream>>>(psum, psq, bn_g, bn_b, scale, shift);
    k_bnapply<<<4096, 256, 0, stream>>>(out, scale, shift);
}